// Round 5
// baseline (180.228 us; speedup 1.0000x reference)
//
#include <hip/hip_runtime.h>
#include <hip/hip_bf16.h>

#define B_ 8
#define T_ 2048
#define C_ 768
#define H_ 64
#define BT_ (B_*T_)

typedef __attribute__((ext_vector_type(8))) short bf16x8;
typedef __attribute__((ext_vector_type(4))) float f32x4;

__device__ __forceinline__ unsigned short f2bf(float x) {
    __hip_bfloat16 h = __float2bfloat16(x);   // RNE
    return __builtin_bit_cast(unsigned short, h);
}

__device__ __forceinline__ bf16x8 cvt8(float4 a, float4 b) {
    bf16x8 r;
    r[0] = (short)f2bf(a.x); r[1] = (short)f2bf(a.y);
    r[2] = (short)f2bf(a.z); r[3] = (short)f2bf(a.w);
    r[4] = (short)f2bf(b.x); r[5] = (short)f2bf(b.y);
    r[6] = (short)f2bf(b.z); r[7] = (short)f2bf(b.w);
    return r;
}

// ------------- W prep (coalesced LDS transpose): WT[m*64+n][k] = bf16(W_m[k][n])
__global__ __launch_bounds__(256) void wprep(
    const float* __restrict__ Wq, const float* __restrict__ Wk,
    const float* __restrict__ Wv, unsigned short* __restrict__ WT)
{
    __shared__ float tile[64][65];
    const int bidx = blockIdx.x;             // 36 = 3 m * 12 k-tiles
    const int m = bidx / 12, kt = bidx % 12;
    const float* __restrict__ W = (m == 0) ? Wq : (m == 1) ? Wk : Wv;
    const int t = threadIdx.x;
    const int n = t & 63, kr = t >> 6;
    #pragma unroll
    for (int r = kr; r < 64; r += 4)
        tile[r][n] = W[(size_t)(kt * 64 + r) * H_ + n];   // coalesced 256B rows
    __syncthreads();
    const int n2 = t >> 2, k0 = (t & 3) * 16;
    #pragma unroll
    for (int g = 0; g < 4; g++) {
        ushort4 u;
        u.x = f2bf(tile[k0 + g * 4 + 0][n2]);
        u.y = f2bf(tile[k0 + g * 4 + 1][n2]);
        u.z = f2bf(tile[k0 + g * 4 + 2][n2]);
        u.w = f2bf(tile[k0 + g * 4 + 3][n2]);
        *(ushort4*)(WT + (size_t)(m * 64 + n2) * C_ + kt * 64 + k0 + g * 4) = u;
    }
}

// ------------- QKV via MFMA: barrier-free N-split --------------------------------
// Wave = 16 tokens x 3 f-groups (48 of 192 output cols) over FULL C=768.
// Complete dot products per wave: no LDS, no merge, no __syncthreads.
// Double-buffered loads: iter i+1's W/x issued before iter i's MFMAs.
__global__ __launch_bounds__(256) void qkv_kernel(
    const float* __restrict__ x, const unsigned short* __restrict__ WT,
    unsigned short* __restrict__ qo, unsigned short* __restrict__ ko,
    unsigned short* __restrict__ vTo)
{
    const int tid  = threadIdx.x;
    const int w    = tid >> 6;              // f-group set 0..3
    const int lane = tid & 63;
    const int q16  = lane & 15, quad = lane >> 4;
    const int rowBase = blockIdx.x << 4;
    const int row  = rowBase + q16;
    const int b    = rowBase >> 11, t0 = rowBase & (T_ - 1);
    const int f0   = w * 3;

    const float* __restrict__ xp = x + (size_t)row * C_ + quad * 8;
    const unsigned short* __restrict__ wp = WT + (size_t)(f0 * 16 + q16) * C_ + quad * 8;

    f32x4 acc[3] = {};
    float4 xa0 = *(const float4*)(xp);
    float4 xa1 = *(const float4*)(xp + 4);
    bf16x8 wfA[3];
    #pragma unroll
    for (int j = 0; j < 3; j++) wfA[j] = *(const bf16x8*)(wp + (size_t)j * 16 * C_);

    #pragma unroll 2
    for (int kk = 0; kk < C_; kk += 32) {
        const int nk = (kk + 32 < C_) ? kk + 32 : 0;   // wrap: harmless redundant load
        float4 xb0 = *(const float4*)(xp + nk);
        float4 xb1 = *(const float4*)(xp + nk + 4);
        bf16x8 wfB[3];
        #pragma unroll
        for (int j = 0; j < 3; j++) wfB[j] = *(const bf16x8*)(wp + nk + (size_t)j * 16 * C_);

        bf16x8 xf = cvt8(xa0, xa1);
        #pragma unroll
        for (int j = 0; j < 3; j++)
            acc[j] = __builtin_amdgcn_mfma_f32_16x16x32_bf16(wfA[j], xf, acc[j], 0, 0, 0);

        xa0 = xb0; xa1 = xb1;
        #pragma unroll
        for (int j = 0; j < 3; j++) wfA[j] = wfB[j];
    }

    #pragma unroll
    for (int j = 0; j < 3; j++) {
        const int f = f0 + j;               // wave-uniform
        if (f < 8) {
            ushort4 u;
            u.x = f2bf(acc[j][0]); u.y = f2bf(acc[j][1]);
            u.z = f2bf(acc[j][2]); u.w = f2bf(acc[j][3]);
            unsigned short* __restrict__ dst = (f < 4) ? qo : ko;
            *(ushort4*)(dst + (size_t)row * H_ + (f & 3) * 16 + quad * 4) = u;
        } else {
            #pragma unroll
            for (int r = 0; r < 4; r++) {
                int h = (f - 8) * 16 + quad * 4 + r;
                vTo[((size_t)(b * H_) + h) * T_ + t0 + q16] = f2bf(acc[j][r]);
            }
        }
    }
}

// ------------- MFMA flash attention: 4 waves/block k-split, NO in-loop barriers -
__global__ __launch_bounds__(256) void attn_kernel(
    const unsigned short* __restrict__ qB, const unsigned short* __restrict__ kB,
    const unsigned short* __restrict__ vT, const float* __restrict__ mask,
    float* __restrict__ out)
{
    __shared__ __align__(16) unsigned short pS[4][16][88];  // wave-private P tiles
    __shared__ float oS[3][64][17];
    __shared__ float mlS[3][64][2];

    const int tid  = threadIdx.x;
    const int w    = tid >> 6;
    const int lane = tid & 63;
    const int q16  = lane & 15;
    const int quad = lane >> 4;
    const int bid  = blockIdx.x;
    const int b    = bid & 7;                    // batches interleaved
    const int qt   = 127 - (bid >> 3);           // heavy q-tiles first
    const int qrow = (qt << 4) + q16;

    const size_t qoff = ((size_t)(b * T_) + qrow) * H_ + quad * 8;
    bf16x8 qf0 = *(const bf16x8*)(qB + qoff);
    bf16x8 qf1 = *(const bf16x8*)(qB + qoff + 32);
    // fold 1/sqrt(64) and log2(e): softmax runs in base-2 domain
    const float maskv = mask[b * T_ + qrow] * 0.125f * 1.44269504f;

    f32x4 o[4] = {};
    float m_run = -__builtin_inff();
    float l_run = 0.f;

    const int niter = ((qt << 4) + 16 + 63) >> 6;   // 64-wide k tiles
    for (int kt = w; kt < niter; kt += 4) {
        const int kbase = kt << 6;

        // ---- K and V fragment loads (issued together; V covers softmax latency)
        bf16x8 kf[8], vf[8];
        #pragma unroll
        for (int sub = 0; sub < 4; sub++) {
            const unsigned short* kp = kB + ((size_t)(b * T_) + kbase + sub * 16 + q16) * H_ + quad * 8;
            kf[2 * sub]     = *(const bf16x8*)(kp);
            kf[2 * sub + 1] = *(const bf16x8*)(kp + 32);
        }
        #pragma unroll
        for (int ht = 0; ht < 4; ht++) {
            const unsigned short* vp = vT + ((size_t)(b * H_) + ht * 16 + q16) * T_ + kbase + quad * 8;
            vf[2 * ht]     = *(const bf16x8*)(vp);
            vf[2 * ht + 1] = *(const bf16x8*)(vp + 32);
        }

        // ---- S^T = K.Q^T : D[k_local][q]
        f32x4 sa[4] = {};
        #pragma unroll
        for (int sub = 0; sub < 4; sub++) {
            sa[sub] = __builtin_amdgcn_mfma_f32_16x16x32_bf16(kf[2 * sub],     qf0, sa[sub], 0, 0, 0);
            sa[sub] = __builtin_amdgcn_mfma_f32_16x16x32_bf16(kf[2 * sub + 1], qf1, sa[sub], 0, 0, 0);
        }

        // ---- reference semantics: s = mask*qk/8 (log2 dom); s==0 -> -inf; causal
        float s[16];
        #pragma unroll
        for (int sub = 0; sub < 4; sub++)
            #pragma unroll
            for (int r = 0; r < 4; r++) {
                int kidx = kbase + sub * 16 + quad * 4 + r;
                float sv = sa[sub][r] * maskv;
                sv = (sv == 0.f) ? -__builtin_inff() : sv;
                sv = (kidx > qrow) ? -__builtin_inff() : sv;
                s[sub * 4 + r] = sv;
            }

        // ---- online softmax (base-2). xor-16/32 reduce across the 4 lane-quads.
        float mx = s[0];
        #pragma unroll
        for (int i2 = 1; i2 < 16; i2++) mx = fmaxf(mx, s[i2]);
        mx = fmaxf(mx, __shfl_xor(mx, 16));
        mx = fmaxf(mx, __shfl_xor(mx, 32));
        float m_new = fmaxf(m_run, mx);
        float m_use = (m_new == -__builtin_inff()) ? 0.f : m_new;
        float alpha = exp2f(m_run - m_use);
        float p[16], psum = 0.f;
        #pragma unroll
        for (int i2 = 0; i2 < 16; i2++) { p[i2] = exp2f(s[i2] - m_use); psum += p[i2]; }
        psum += __shfl_xor(psum, 16);
        psum += __shfl_xor(psum, 32);
        l_run = l_run * alpha + psum;
        m_run = m_new;
        #pragma unroll
        for (int ht = 0; ht < 4; ht++)
            #pragma unroll
            for (int r = 0; r < 4; r++) o[ht][r] *= alpha;

        // ---- P^T -> wave-private LDS as P[q][k] bf16 (intra-wave: no barrier)
        #pragma unroll
        for (int sub = 0; sub < 4; sub++) {
            unsigned int lo = (unsigned int)f2bf(p[sub * 4 + 0]) | ((unsigned int)f2bf(p[sub * 4 + 1]) << 16);
            unsigned int hi = (unsigned int)f2bf(p[sub * 4 + 2]) | ((unsigned int)f2bf(p[sub * 4 + 3]) << 16);
            *(uint2*)&pS[w][q16][sub * 16 + quad * 4] = make_uint2(lo, hi);
        }
        bf16x8 pf0 = *(const bf16x8*)&pS[w][q16][quad * 8];
        bf16x8 pf1 = *(const bf16x8*)&pS[w][q16][32 + quad * 8];

        // ---- O^T += V^T.P^T
        #pragma unroll
        for (int ht = 0; ht < 4; ht++) {
            o[ht] = __builtin_amdgcn_mfma_f32_16x16x32_bf16(vf[2 * ht],     pf0, o[ht], 0, 0, 0);
            o[ht] = __builtin_amdgcn_mfma_f32_16x16x32_bf16(vf[2 * ht + 1], pf1, o[ht], 0, 0, 0);
        }
    }

    // ---- merge the 4 waves' online-softmax states
    if (w > 0) {
        mlS[w - 1][lane][0] = m_run;
        mlS[w - 1][lane][1] = l_run;
        #pragma unroll
        for (int ht = 0; ht < 4; ht++)
            #pragma unroll
            for (int r = 0; r < 4; r++) oS[w - 1][lane][ht * 4 + r] = o[ht][r];
    }
    __syncthreads();
    if (w == 0) {
        float mm[3], ll[3];
        float m = m_run;
        #pragma unroll
        for (int j = 0; j < 3; j++) {
            mm[j] = mlS[j][lane][0]; ll[j] = mlS[j][lane][1];
            m = fmaxf(m, mm[j]);
        }
        float mu = (m == -__builtin_inff()) ? 0.f : m;
        float a0 = exp2f(m_run - mu);
        float aj[3];
        float l = l_run * a0;
        #pragma unroll
        for (int j = 0; j < 3; j++) { aj[j] = exp2f(mm[j] - mu); l += ll[j] * aj[j]; }
        float invl = (l > 0.f) ? (1.f / l) : 0.f;   // fully-masked row -> 0
        #pragma unroll
        for (int ht = 0; ht < 4; ht++) {
            float4 ov;
            float vx = o[ht][0] * a0, vy = o[ht][1] * a0, vz = o[ht][2] * a0, vw2 = o[ht][3] * a0;
            #pragma unroll
            for (int j = 0; j < 3; j++) {
                vx += oS[j][lane][ht * 4 + 0] * aj[j];
                vy += oS[j][lane][ht * 4 + 1] * aj[j];
                vz += oS[j][lane][ht * 4 + 2] * aj[j];
                vw2 += oS[j][lane][ht * 4 + 3] * aj[j];
            }
            ov.x = vx * invl; ov.y = vy * invl; ov.z = vz * invl; ov.w = vw2 * invl;
            *(float4*)(out + ((size_t)(b * T_) + qrow) * H_ + ht * 16 + quad * 4) = ov;
        }
    }
}

extern "C" void kernel_launch(void* const* d_in, const int* in_sizes, int n_in,
                              void* d_out, int out_size, void* d_ws, size_t ws_size,
                              hipStream_t stream) {
    const float* x    = (const float*)d_in[0];
    const float* mask = (const float*)d_in[1];
    const float* Wq   = (const float*)d_in[2];
    const float* Wk   = (const float*)d_in[3];
    const float* Wv   = (const float*)d_in[4];
    float* out = (float*)d_out;

    unsigned short* qw = (unsigned short*)d_ws;            // bf16 [B,T,H]
    unsigned short* kw = qw + (size_t)BT_ * H_;            // bf16 [B,T,H]
    unsigned short* vw = kw + (size_t)BT_ * H_;            // bf16 [B,H,T]
    unsigned short* wt = vw + (size_t)BT_ * H_;            // bf16 [192][768]

    wprep<<<36, 256, 0, stream>>>(Wq, Wk, Wv, wt);
    qkv_kernel<<<BT_ / 16, 256, 0, stream>>>(x, wt, qw, kw, vw);
    attn_kernel<<<B_ * (T_ / 16), 256, 0, stream>>>(qw, kw, vw, mask, out);
}

// Round 6
// 160.610 us; speedup vs baseline: 1.1221x; 1.1221x over previous
//
#include <hip/hip_runtime.h>
#include <hip/hip_bf16.h>

#define B_ 8
#define T_ 2048
#define C_ 768
#define H_ 64
#define BT_ (B_*T_)

typedef __attribute__((ext_vector_type(8))) short bf16x8;
typedef __attribute__((ext_vector_type(4))) float f32x4;

__device__ __forceinline__ unsigned short f2bf(float x) {
    __hip_bfloat16 h = __float2bfloat16(x);   // RNE
    return __builtin_bit_cast(unsigned short, h);
}

// ------------- W prep (coalesced LDS transpose): WT[m*64+n][k] = bf16(W_m[k][n])
__global__ __launch_bounds__(256) void wprep(
    const float* __restrict__ Wq, const float* __restrict__ Wk,
    const float* __restrict__ Wv, unsigned short* __restrict__ WT)
{
    __shared__ float tile[64][65];
    const int bidx = blockIdx.x;             // 36 = 3 m * 12 k-tiles
    const int m = bidx / 12, kt = bidx % 12;
    const float* __restrict__ W = (m == 0) ? Wq : (m == 1) ? Wk : Wv;
    const int t = threadIdx.x;
    const int n = t & 63, kr = t >> 6;
    #pragma unroll
    for (int r = kr; r < 64; r += 4)
        tile[r][n] = W[(size_t)(kt * 64 + r) * H_ + n];   // coalesced 256B rows
    __syncthreads();
    const int n2 = t >> 2, k0 = (t & 3) * 16;
    #pragma unroll
    for (int g = 0; g < 4; g++) {
        ushort4 u;
        u.x = f2bf(tile[k0 + g * 4 + 0][n2]);
        u.y = f2bf(tile[k0 + g * 4 + 1][n2]);
        u.z = f2bf(tile[k0 + g * 4 + 2][n2]);
        u.w = f2bf(tile[k0 + g * 4 + 3][n2]);
        *(ushort4*)(WT + (size_t)(m * 64 + n2) * C_ + kt * 64 + k0 + g * 4) = u;
    }
}

// ------------- QKV via MFMA: barrier-free N-split, LDS-staged x -----------------
// Block = 16 tokens. Stage x once: coalesced fp32 reads -> bf16 -> LDS in exact
// B-fragment order (xF[chunk][lane][8]) so compute reads are 1 ds_read_b128.
// Wave w computes f-groups w*3..w*3+2 over full C: no merge, no in-loop barrier.
// W prefetched 2 chunks deep (6 global loads in flight).
__global__ __launch_bounds__(256) void qkv_kernel(
    const float* __restrict__ x, const unsigned short* __restrict__ WT,
    unsigned short* __restrict__ qo, unsigned short* __restrict__ ko,
    unsigned short* __restrict__ vTo)
{
    __shared__ __align__(16) unsigned short xF[24 * 512];   // 24 chunks x 64 lanes x 8
    const int tid  = threadIdx.x;
    const int rowBase = blockIdx.x << 4;

    // ---- stage x: thread t reads row t>>4, 12 float4s, writes fragment-order LDS
    {
        const int r  = tid >> 4;                 // 0..15
        const int c0 = (tid & 15) << 2;          // 0,4,..,60
        const float* __restrict__ xrow = x + (size_t)(rowBase + r) * C_;
        #pragma unroll
        for (int i = 0; i < 12; i++) {
            const int k = c0 + 64 * i;
            float4 v = *(const float4*)(xrow + k);
            ushort4 u;
            u.x = f2bf(v.x); u.y = f2bf(v.y); u.z = f2bf(v.z); u.w = f2bf(v.w);
            const int c    = k >> 5;             // chunk
            const int quad = (k >> 3) & 3;
            const int j0   = k & 7;              // 0 or 4
            *(ushort4*)&xF[c * 512 + (r + (quad << 4)) * 8 + j0] = u;
        }
    }
    __syncthreads();

    const int w    = tid >> 6;                   // f-set 0..3
    const int lane = tid & 63;
    const int q16  = lane & 15, quad = lane >> 4;
    const int row  = rowBase + q16;
    const int b    = rowBase >> 11, t0 = rowBase & (T_ - 1);
    const int f0   = w * 3;

    const unsigned short* __restrict__ wp = WT + (size_t)(f0 * 16 + q16) * C_ + quad * 8;

    f32x4 acc[3] = {};
    bf16x8 wA[3], wB[3], xA;
    #pragma unroll
    for (int j = 0; j < 3; j++) {
        wA[j] = *(const bf16x8*)(wp + (size_t)j * 16 * C_);
        wB[j] = *(const bf16x8*)(wp + 32 + (size_t)j * 16 * C_);
    }
    xA = *(const bf16x8*)&xF[lane * 8];

    #pragma unroll
    for (int c = 0; c < 24; c++) {
        bf16x8 wN[3], xN;
        if (c + 2 < 24) {
            #pragma unroll
            for (int j = 0; j < 3; j++)
                wN[j] = *(const bf16x8*)(wp + (c + 2) * 32 + (size_t)j * 16 * C_);
        }
        if (c + 1 < 24) xN = *(const bf16x8*)&xF[(c + 1) * 512 + lane * 8];
        #pragma unroll
        for (int j = 0; j < 3; j++)
            acc[j] = __builtin_amdgcn_mfma_f32_16x16x32_bf16(wA[j], xA, acc[j], 0, 0, 0);
        #pragma unroll
        for (int j = 0; j < 3; j++) { wA[j] = wB[j]; wB[j] = wN[j]; }
        xA = xN;
    }

    #pragma unroll
    for (int j = 0; j < 3; j++) {
        const int f = f0 + j;                    // wave-uniform
        if (f < 8) {
            ushort4 u;
            u.x = f2bf(acc[j][0]); u.y = f2bf(acc[j][1]);
            u.z = f2bf(acc[j][2]); u.w = f2bf(acc[j][3]);
            unsigned short* __restrict__ dst = (f < 4) ? qo : ko;
            *(ushort4*)(dst + (size_t)row * H_ + (f & 3) * 16 + quad * 4) = u;
        } else {
            #pragma unroll
            for (int r = 0; r < 4; r++) {
                int h = (f - 8) * 16 + quad * 4 + r;
                vTo[((size_t)(b * H_) + h) * T_ + t0 + q16] = f2bf(acc[j][r]);
            }
        }
    }
}

// ------------- MFMA flash attention: 4 waves/block k-split, NO in-loop barriers -
__global__ __launch_bounds__(256) void attn_kernel(
    const unsigned short* __restrict__ qB, const unsigned short* __restrict__ kB,
    const unsigned short* __restrict__ vT, const float* __restrict__ mask,
    float* __restrict__ out)
{
    __shared__ __align__(16) unsigned short pS[4][16][88];  // wave-private P tiles
    __shared__ float oS[3][64][17];
    __shared__ float mlS[3][64][2];

    const int tid  = threadIdx.x;
    const int w    = tid >> 6;
    const int lane = tid & 63;
    const int q16  = lane & 15;
    const int quad = lane >> 4;
    const int bid  = blockIdx.x;
    const int b    = bid & 7;                    // batches interleaved
    const int qt   = 127 - (bid >> 3);           // heavy q-tiles first
    const int qrow = (qt << 4) + q16;

    const size_t qoff = ((size_t)(b * T_) + qrow) * H_ + quad * 8;
    bf16x8 qf0 = *(const bf16x8*)(qB + qoff);
    bf16x8 qf1 = *(const bf16x8*)(qB + qoff + 32);
    // fold 1/sqrt(64) and log2(e): softmax runs in base-2 domain
    const float maskv = mask[b * T_ + qrow] * 0.125f * 1.44269504f;

    f32x4 o[4] = {};
    float m_run = -__builtin_inff();
    float l_run = 0.f;

    const int niter = ((qt << 4) + 16 + 63) >> 6;   // 64-wide k tiles
    for (int kt = w; kt < niter; kt += 4) {
        const int kbase = kt << 6;

        // ---- K and V fragment loads (issued together; V covers softmax latency)
        bf16x8 kf[8], vf[8];
        #pragma unroll
        for (int sub = 0; sub < 4; sub++) {
            const unsigned short* kp = kB + ((size_t)(b * T_) + kbase + sub * 16 + q16) * H_ + quad * 8;
            kf[2 * sub]     = *(const bf16x8*)(kp);
            kf[2 * sub + 1] = *(const bf16x8*)(kp + 32);
        }
        #pragma unroll
        for (int ht = 0; ht < 4; ht++) {
            const unsigned short* vp = vT + ((size_t)(b * H_) + ht * 16 + q16) * T_ + kbase + quad * 8;
            vf[2 * ht]     = *(const bf16x8*)(vp);
            vf[2 * ht + 1] = *(const bf16x8*)(vp + 32);
        }

        // ---- S^T = K.Q^T : D[k_local][q]
        f32x4 sa[4] = {};
        #pragma unroll
        for (int sub = 0; sub < 4; sub++) {
            sa[sub] = __builtin_amdgcn_mfma_f32_16x16x32_bf16(kf[2 * sub],     qf0, sa[sub], 0, 0, 0);
            sa[sub] = __builtin_amdgcn_mfma_f32_16x16x32_bf16(kf[2 * sub + 1], qf1, sa[sub], 0, 0, 0);
        }

        // ---- reference semantics: s = mask*qk/8 (log2 dom); s==0 -> -inf; causal
        float s[16];
        #pragma unroll
        for (int sub = 0; sub < 4; sub++)
            #pragma unroll
            for (int r = 0; r < 4; r++) {
                int kidx = kbase + sub * 16 + quad * 4 + r;
                float sv = sa[sub][r] * maskv;
                sv = (sv == 0.f) ? -__builtin_inff() : sv;
                sv = (kidx > qrow) ? -__builtin_inff() : sv;
                s[sub * 4 + r] = sv;
            }

        // ---- online softmax (base-2). xor-16/32 reduce across the 4 lane-quads.
        float mx = s[0];
        #pragma unroll
        for (int i2 = 1; i2 < 16; i2++) mx = fmaxf(mx, s[i2]);
        mx = fmaxf(mx, __shfl_xor(mx, 16));
        mx = fmaxf(mx, __shfl_xor(mx, 32));
        float m_new = fmaxf(m_run, mx);
        float m_use = (m_new == -__builtin_inff()) ? 0.f : m_new;
        float alpha = exp2f(m_run - m_use);
        float p[16], psum = 0.f;
        #pragma unroll
        for (int i2 = 0; i2 < 16; i2++) { p[i2] = exp2f(s[i2] - m_use); psum += p[i2]; }
        psum += __shfl_xor(psum, 16);
        psum += __shfl_xor(psum, 32);
        l_run = l_run * alpha + psum;
        m_run = m_new;
        #pragma unroll
        for (int ht = 0; ht < 4; ht++)
            #pragma unroll
            for (int r = 0; r < 4; r++) o[ht][r] *= alpha;

        // ---- P^T -> wave-private LDS as P[q][k] bf16 (intra-wave: no barrier)
        #pragma unroll
        for (int sub = 0; sub < 4; sub++) {
            unsigned int lo = (unsigned int)f2bf(p[sub * 4 + 0]) | ((unsigned int)f2bf(p[sub * 4 + 1]) << 16);
            unsigned int hi = (unsigned int)f2bf(p[sub * 4 + 2]) | ((unsigned int)f2bf(p[sub * 4 + 3]) << 16);
            *(uint2*)&pS[w][q16][sub * 16 + quad * 4] = make_uint2(lo, hi);
        }
        bf16x8 pf0 = *(const bf16x8*)&pS[w][q16][quad * 8];
        bf16x8 pf1 = *(const bf16x8*)&pS[w][q16][32 + quad * 8];

        // ---- O^T += V^T.P^T
        #pragma unroll
        for (int ht = 0; ht < 4; ht++) {
            o[ht] = __builtin_amdgcn_mfma_f32_16x16x32_bf16(vf[2 * ht],     pf0, o[ht], 0, 0, 0);
            o[ht] = __builtin_amdgcn_mfma_f32_16x16x32_bf16(vf[2 * ht + 1], pf1, o[ht], 0, 0, 0);
        }
    }

    // ---- merge the 4 waves' online-softmax states
    if (w > 0) {
        mlS[w - 1][lane][0] = m_run;
        mlS[w - 1][lane][1] = l_run;
        #pragma unroll
        for (int ht = 0; ht < 4; ht++)
            #pragma unroll
            for (int r = 0; r < 4; r++) oS[w - 1][lane][ht * 4 + r] = o[ht][r];
    }
    __syncthreads();
    if (w == 0) {
        float mm[3], ll[3];
        float m = m_run;
        #pragma unroll
        for (int j = 0; j < 3; j++) {
            mm[j] = mlS[j][lane][0]; ll[j] = mlS[j][lane][1];
            m = fmaxf(m, mm[j]);
        }
        float mu = (m == -__builtin_inff()) ? 0.f : m;
        float a0 = exp2f(m_run - mu);
        float aj[3];
        float l = l_run * a0;
        #pragma unroll
        for (int j = 0; j < 3; j++) { aj[j] = exp2f(mm[j] - mu); l += ll[j] * aj[j]; }
        float invl = (l > 0.f) ? (1.f / l) : 0.f;   // fully-masked row -> 0
        #pragma unroll
        for (int ht = 0; ht < 4; ht++) {
            float4 ov;
            float vx = o[ht][0] * a0, vy = o[ht][1] * a0, vz = o[ht][2] * a0, vw2 = o[ht][3] * a0;
            #pragma unroll
            for (int j = 0; j < 3; j++) {
                vx += oS[j][lane][ht * 4 + 0] * aj[j];
                vy += oS[j][lane][ht * 4 + 1] * aj[j];
                vz += oS[j][lane][ht * 4 + 2] * aj[j];
                vw2 += oS[j][lane][ht * 4 + 3] * aj[j];
            }
            ov.x = vx * invl; ov.y = vy * invl; ov.z = vz * invl; ov.w = vw2 * invl;
            *(float4*)(out + ((size_t)(b * T_) + qrow) * H_ + ht * 16 + quad * 4) = ov;
        }
    }
}

extern "C" void kernel_launch(void* const* d_in, const int* in_sizes, int n_in,
                              void* d_out, int out_size, void* d_ws, size_t ws_size,
                              hipStream_t stream) {
    const float* x    = (const float*)d_in[0];
    const float* mask = (const float*)d_in[1];
    const float* Wq   = (const float*)d_in[2];
    const float* Wk   = (const float*)d_in[3];
    const float* Wv   = (const float*)d_in[4];
    float* out = (float*)d_out;

    unsigned short* qw = (unsigned short*)d_ws;            // bf16 [B,T,H]
    unsigned short* kw = qw + (size_t)BT_ * H_;            // bf16 [B,T,H]
    unsigned short* vw = kw + (size_t)BT_ * H_;            // bf16 [B,H,T]
    unsigned short* wt = vw + (size_t)BT_ * H_;            // bf16 [192][768]

    wprep<<<36, 256, 0, stream>>>(Wq, Wk, Wv, wt);
    qkv_kernel<<<BT_ / 16, 256, 0, stream>>>(x, wt, qw, kw, vw);
    attn_kernel<<<B_ * (T_ / 16), 256, 0, stream>>>(qw, kw, vw, mask, out);
}